// Round 10
// baseline (140.981 us; speedup 1.0000x reference)
//
#include <hip/hip_runtime.h>

// Chamfer distance: srcs, tgts [B=8, D=3, N=4096] f32 -> scalar f32
//
// Round 10: INSTRUMENTATION round. R9's symmetric tile kernel, with the
// 8x8 micro-block compute repeated REP=4x in-kernel (CSE defeated via
// empty asm "+v" clobbers on sw/uw; min-folds idempotent -> identical
// output). Purpose: push cd_tile above the 41.5us poison-fill so its
// counters (VGPR/VALUBusy/Occupancy) appear in top-5, and solve
// T_tile = (total - floor - reduce)/REP. Expect total to INCREASE.

#define CD_B 8
#define CD_N 4096
#define BLK 256
#define TIL 128               // tile edge
#define NT  (CD_N / TIL)      // 32 tiles per axis
#define QI 8                  // rows per thread
#define QJ 8                  // cols per thread
#define NQ (2 * CD_B * CD_N)  // 65536 = 32768 row-entries + 32768 col-entries
#define REP 4                 // in-kernel repeat (measurement only)

__device__ __forceinline__ float min3f(float m, float a, float b) {
  asm("v_min3_f32 %0, %1, %2, %0" : "+v"(m) : "v"(a), "v"(b));
  return m;
}

// ws layout: float ws[NT][NQ]  (8 MB)
__global__ __launch_bounds__(BLK) void cd_tile(
    const float* __restrict__ srcs, const float* __restrict__ tgts,
    float* __restrict__ ws, float* __restrict__ out) {
  const int bid = blockIdx.x;            // 8192 blocks
  const int jt  = bid & (NT - 1);        // 5 bits
  const int it  = (bid >> 5) & (NT - 1); // 5 bits
  const int b   = bid >> 10;             // 3 bits
  const int tid = threadIdx.x;
  const int tx  = tid & 15;              // j-direction (lane bits 0-3)
  const int ty  = tid >> 4;              // i-direction

  if (bid == 0 && tid == 0) out[0] = 0.0f;  // stream-ordered before cd_reduce

  const float* sb = srcs + b * 3 * CD_N;
  const float* tb = tgts + b * 3 * CD_N;
  const int i0 = it * TIL + ty * QI;
  const int j0 = jt * TIL + tx * QJ;

  // Register-resident coordinates: 8 srcs rows, 8 tgts cols.
  float sx[QI], sy[QI], sz[QI], sw[QI];
  float ux[QJ], uy[QJ], uz[QJ], uw[QJ];
  *(float4*)&sx[0] = *(const float4*)(sb + i0);
  *(float4*)&sx[4] = *(const float4*)(sb + i0 + 4);
  *(float4*)&sy[0] = *(const float4*)(sb + CD_N + i0);
  *(float4*)&sy[4] = *(const float4*)(sb + CD_N + i0 + 4);
  *(float4*)&sz[0] = *(const float4*)(sb + 2 * CD_N + i0);
  *(float4*)&sz[4] = *(const float4*)(sb + 2 * CD_N + i0 + 4);
  *(float4*)&ux[0] = *(const float4*)(tb + j0);
  *(float4*)&ux[4] = *(const float4*)(tb + j0 + 4);
  *(float4*)&uy[0] = *(const float4*)(tb + CD_N + j0);
  *(float4*)&uy[4] = *(const float4*)(tb + CD_N + j0 + 4);
  *(float4*)&uz[0] = *(const float4*)(tb + 2 * CD_N + j0);
  *(float4*)&uz[4] = *(const float4*)(tb + 2 * CD_N + j0 + 4);
#pragma unroll
  for (int u = 0; u < QI; ++u)
    sw[u] = fmaf(sx[u], sx[u], fmaf(sy[u], sy[u], sz[u] * sz[u]));
#pragma unroll
  for (int u = 0; u < QJ; ++u) {
    uw[u] = fmaf(ux[u], ux[u], fmaf(uy[u], uy[u], uz[u] * uz[u]));
    ux[u] *= -2.0f; uy[u] *= -2.0f; uz[u] *= -2.0f;
  }

  float rm[QI], cm[QJ];
#pragma unroll
  for (int u = 0; u < QI; ++u) rm[u] = 3.4e38f;
#pragma unroll
  for (int u = 0; u < QJ; ++u) cm[u] = 3.4e38f;

  for (int rep = 0; rep < REP; ++rep) {
    // Defeat CSE across reps: make the rank-1 bases opaque. Output is
    // unchanged (min is idempotent; values are bit-identical each rep).
    asm volatile("" : "+v"(sw[0]), "+v"(sw[1]), "+v"(sw[2]), "+v"(sw[3]),
                      "+v"(sw[4]), "+v"(sw[5]), "+v"(sw[6]), "+v"(sw[7]),
                      "+v"(uw[0]), "+v"(uw[1]), "+v"(uw[2]), "+v"(uw[3]),
                      "+v"(uw[4]), "+v"(uw[5]), "+v"(uw[6]), "+v"(uw[7]));
    // 8x8 register tile in 2x2 micro-blocks: 20 inst / 4 pairs.
#pragma unroll
    for (int i = 0; i < QI; i += 2) {
#pragma unroll
      for (int j = 0; j < QJ; j += 2) {
        float b00 = sw[i] + uw[j];
        float b01 = sw[i] + uw[j + 1];
        float b10 = sw[i + 1] + uw[j];
        float b11 = sw[i + 1] + uw[j + 1];
        float v00 = fmaf(sx[i], ux[j], fmaf(sy[i], uy[j], fmaf(sz[i], uz[j], b00)));
        float v01 = fmaf(sx[i], ux[j+1], fmaf(sy[i], uy[j+1], fmaf(sz[i], uz[j+1], b01)));
        float v10 = fmaf(sx[i+1], ux[j], fmaf(sy[i+1], uy[j], fmaf(sz[i+1], uz[j], b10)));
        float v11 = fmaf(sx[i+1], ux[j+1], fmaf(sy[i+1], uy[j+1], fmaf(sz[i+1], uz[j+1], b11)));
        rm[i]     = min3f(rm[i],     v00, v01);
        rm[i + 1] = min3f(rm[i + 1], v10, v11);
        cm[j]     = min3f(cm[j],     v00, v10);
        cm[j + 1] = min3f(cm[j + 1], v01, v11);
      }
    }
  }

  // Row mins: reduce across tx = lane bits 0-3 (in-wave shuffles).
#pragma unroll
  for (int u = 0; u < QI; ++u) {
    float r = rm[u];
    r = fminf(r, __shfl_xor(r, 1, 64));
    r = fminf(r, __shfl_xor(r, 2, 64));
    r = fminf(r, __shfl_xor(r, 4, 64));
    r = fminf(r, __shfl_xor(r, 8, 64));
    rm[u] = r;
  }
  if (tx == 0) {
    float* wrow = ws + (size_t)jt * NQ + b * CD_N + i0;
    *(float4*)&wrow[0] = make_float4(rm[0], rm[1], rm[2], rm[3]);
    *(float4*)&wrow[4] = make_float4(rm[4], rm[5], rm[6], rm[7]);
  }

  // Col mins: reduce ty&3 in-wave (lane bits 4-5), then across 4 waves via LDS.
#pragma unroll
  for (int u = 0; u < QJ; ++u) {
    float c = cm[u];
    c = fminf(c, __shfl_xor(c, 16, 64));
    c = fminf(c, __shfl_xor(c, 32, 64));
    cm[u] = c;
  }
  __shared__ float C[4][TIL];  // 2 KB
  if ((ty & 3) == 0) {
#pragma unroll
    for (int u = 0; u < QJ; ++u) C[ty >> 2][tx * QJ + u] = cm[u];
  }
  __syncthreads();
  if (tid < TIL) {
    float c = fminf(fminf(C[0][tid], C[1][tid]), fminf(C[2][tid], C[3][tid]));
    ws[(size_t)it * NQ + CD_B * CD_N + b * CD_N + jt * TIL + tid] = c;
  }
}

__global__ __launch_bounds__(BLK) void cd_reduce(
    const float* __restrict__ ws, float* __restrict__ out) {
  const int q = blockIdx.x * BLK + threadIdx.x;  // 65536 threads
  float m0 = ws[q];
  float m1 = ws[(size_t)1 * NQ + q];
#pragma unroll
  for (int k = 2; k < NT; k += 2) {
    m0 = fminf(m0, ws[(size_t)k * NQ + q]);
    m1 = fminf(m1, ws[(size_t)(k + 1) * NQ + q]);
  }
  float m = fminf(m0, m1);

  for (int off = 32; off; off >>= 1) m += __shfl_down(m, off, 64);
  __shared__ float wsum[BLK / 64];
  if ((threadIdx.x & 63) == 0) wsum[threadIdx.x >> 6] = m;
  __syncthreads();
  if (threadIdx.x == 0) {
    float s = (wsum[0] + wsum[1]) + (wsum[2] + wsum[3]);
    atomicAdd(out, s * (1.0f / (float)(CD_B * CD_N)));
  }
}

extern "C" void kernel_launch(void* const* d_in, const int* in_sizes, int n_in,
                              void* d_out, int out_size, void* d_ws, size_t ws_size,
                              hipStream_t stream) {
  const float* srcs = (const float*)d_in[0];
  const float* tgts = (const float*)d_in[1];
  float* out = (float*)d_out;
  float* ws = (float*)d_ws;  // NT*NQ*4 = 8 MB

  cd_tile<<<CD_B * NT * NT, BLK, 0, stream>>>(srcs, tgts, ws, out);
  cd_reduce<<<NQ / BLK, BLK, 0, stream>>>(ws, out);
}